// Round 8
// baseline (135.018 us; speedup 1.0000x reference)
//
#include <hip/hip_runtime.h>
#include <hip/hip_fp16.h>

#define IN_F 4096
#define OUT_F 11008
#define FP_F 256
#define NROWS 512
#define BN 32
#define BM 256
#define NGEMM ((OUT_F / BN) * (NROWS / BM))  // 344 * 2 = 688

typedef int v4i __attribute__((ext_vector_type(4)));
typedef int v16i __attribute__((ext_vector_type(16)));
typedef float v4f __attribute__((ext_vector_type(4)));
typedef float v16f __attribute__((ext_vector_type(16)));
typedef _Float16 half8 __attribute__((ext_vector_type(8)));

__device__ __forceinline__ int pack4(v4i a) {
  return (int)((unsigned)(a[0] & 255) | ((unsigned)(a[1] & 255) << 8) |
               ((unsigned)(a[2] & 255) << 16) | ((unsigned)(a[3] & 255) << 24));
}

// 32x32 int8 fragment layout (verified r6/r7): v4i slot = (g*128 + kb32)*64 +
// lane, lane = (row&31) + 32*((k>>4)&1), byte = k&15.

// ---------------- quant: x -> int8 qx (fragment layout) + act + xscale -------
__global__ __launch_bounds__(256) void quant_kernel(
    const float* __restrict__ x, const int* __restrict__ ind,
    signed char* __restrict__ qx, _Float16* __restrict__ act,
    float* __restrict__ xscale)
{
  const int m = blockIdx.x;
  const int t = threadIdx.x;
  __shared__ unsigned char zm[IN_F];
  __shared__ float wmax[4];
  int* zmi = (int*)zm;
  #pragma unroll
  for (int i = 0; i < IN_F / 4 / 256; ++i) zmi[t + i * 256] = 0;
  __syncthreads();
  const int idx = ind[t];
  zm[idx] = 1;
  __syncthreads();

  const float* xr = x + (size_t)m * IN_F;
  float v[16];
  float amax = 0.f;
  const int k0 = t * 16;
  #pragma unroll
  for (int q = 0; q < 4; ++q) {
    v4f f = *(const v4f*)(xr + k0 + q * 4);
    #pragma unroll
    for (int j = 0; j < 4; ++j) {
      float mv = zm[k0 + q * 4 + j] ? 0.f : f[j];
      v[q * 4 + j] = mv;
      amax = fmaxf(amax, fabsf(mv));
    }
  }
  #pragma unroll
  for (int off = 32; off >= 1; off >>= 1)
    amax = fmaxf(amax, __shfl_xor(amax, off));
  if ((t & 63) == 0) wmax[t >> 6] = amax;
  __syncthreads();
  amax = fmaxf(fmaxf(wmax[0], wmax[1]), fmaxf(wmax[2], wmax[3]));
  const float scale = fmaxf(amax / 127.0f, 1e-8f);
  if (t == 0) xscale[m] = scale;
  const float inv = 1.0f / scale;

  union { signed char b[16]; v4i w4; } pk;
  #pragma unroll
  for (int j = 0; j < 16; ++j) {
    float qv = rintf(v[j] * inv);            // round-half-even, like jnp.round
    qv = fminf(fmaxf(qv, -128.f), 127.f);
    pk.b[j] = (signed char)qv;
  }
  ((v4i*)qx)[((m >> 5) * 128 + (t >> 1)) * 64 + (m & 31) + 32 * (t & 1)] = pk.w4;

  act[m * FP_F + t] = (_Float16)xr[idx];
}

// ---------------- fused gemm: q_weight read ONCE, packed in-flight ----------
// Tile 256(M) x 32(N), 4 waves, wave = 64 rows x 32 cols (2 mfrags 32x32x32 i8).
// K streamed in 8 chunks of 512: 64KB int32 staged per chunk (256B contiguous
// per thread), packed in-register, ds_written in fragment order with kc&7
// lane-XOR swizzle, double-buffered 2x16KB, ONE barrier per chunk. Next
// chunk's 16 dwordx4 issued at the top of each interval -> latency hidden
// under 32 MFMAs; loads are consumed pre-barrier so syncthreads' drain is free.
__global__ __launch_bounds__(256) void gemm_kernel(
    const signed char* __restrict__ qx, const int* __restrict__ qw,
    const float* __restrict__ scol, const float* __restrict__ wc,
    const float* __restrict__ bias, const _Float16* __restrict__ act,
    const float* __restrict__ xscale, float* __restrict__ out)
{
  __shared__ v4i blds[2][1024];              // 2 x 16 KB
  const int tid = threadIdx.x;
  const int w = tid >> 6;
  const int l = tid & 63;
  const int mseg = blockIdx.x & 1;           // pair shares B panel (L3 temporal)
  const int ntile = blockIdx.x >> 1;
  const int n0 = ntile * BN;
  const int row0 = mseg * BM + w * 64;

  // staging map: thread -> B row srow (0..31), k-slots kc0 and kc0+8
  const int srow = tid >> 3;
  const int kc0  = tid & 7;
  const v4i* b4 = (const v4i*)(qw + (size_t)(n0 + srow) * IN_F);

  const v4i* qx4 = (const v4i*)qx;
  const int aB0 = ((mseg * 8 + w * 2 + 0) * 128) * 64 + l;
  const int aB1 = ((mseg * 8 + w * 2 + 1) * 128) * 64 + l;

  v4i r[2][8];

#define LOADC(C) do {                                                         \
    _Pragma("unroll")                                                         \
    for (int h = 0; h < 2; ++h)                                               \
      _Pragma("unroll")                                                       \
      for (int j = 0; j < 8; ++j)                                             \
        r[h][j] = b4[(C) * 128 + (kc0 + 8 * h) * 8 + j];                      \
  } while (0)

#define WRITEC(C) do {                                                        \
    _Pragma("unroll")                                                         \
    for (int h = 0; h < 2; ++h) {                                             \
      const int kcL = kc0 + 8 * h;                                            \
      v4i lo, hi;                                                             \
      _Pragma("unroll")                                                       \
      for (int j = 0; j < 4; ++j) {                                           \
        lo[j] = pack4(r[h][j]);                                               \
        hi[j] = pack4(r[h][j + 4]);                                           \
      }                                                                       \
      blds[(C) & 1][kcL * 64 + (srow ^ kc0)]      = lo;                       \
      blds[(C) & 1][kcL * 64 + (srow ^ kc0) + 32] = hi;                       \
    }                                                                         \
  } while (0)

  LOADC(0);
  WRITEC(0);
  __syncthreads();

  v16i acc[2] = {};
  for (int c = 0; c < 8; ++c) {
    if (c < 7) LOADC(c + 1);                 // issue early: hides under MFMAs
    const int cb = (c & 1);
    #pragma unroll
    for (int kc = 0; kc < 16; ++kc) {
      v4i bf = blds[cb][kc * 64 + (l ^ (kc & 7))];
      v4i a0 = qx4[aB0 + (c * 16 + kc) * 64];
      v4i a1 = qx4[aB1 + (c * 16 + kc) * 64];
      acc[0] = __builtin_amdgcn_mfma_i32_32x32x32_i8(a0, bf, acc[0], 0, 0, 0);
      acc[1] = __builtin_amdgcn_mfma_i32_32x32x32_i8(a1, bf, acc[1], 0, 0, 0);
    }
    if (c < 7) WRITEC(c + 1);                // counted vmcnt via reg deps
    __syncthreads();
  }
#undef LOADC
#undef WRITEC

  // epilogue: C/D 32x32 mapping: col = l&31, row = (r&3)+8*(r>>2)+4*(l>>5)
  const float sc = scol[n0 + (l & 31)];
  const float bs = bias[n0 + (l & 31)];
  const int hi4 = 4 * (l >> 5);
  float xs[2][16];
  #pragma unroll
  for (int mf = 0; mf < 2; ++mf)
    #pragma unroll
    for (int rr = 0; rr < 16; ++rr)
      xs[mf][rr] = xscale[row0 + mf * 32 + (rr & 3) + 8 * (rr >> 2) + hi4];

  v16f facc[2];
  #pragma unroll
  for (int mf = 0; mf < 2; ++mf)
    #pragma unroll
    for (int rr = 0; rr < 16; ++rr)
      facc[mf][rr] = (float)acc[mf][rr] * xs[mf][rr] * sc;

  // outlier fp phase: K=256 in 16 steps of 16, 32x32x16 f16 MFMA
  #pragma unroll
  for (int ks = 0; ks < 16; ++ks) {
    const int kk = ks * 16 + (l >> 5) * 8;
    half8 ah[2];
    #pragma unroll
    for (int mf = 0; mf < 2; ++mf) {
      const int arow = row0 + mf * 32 + (l & 31);
      ah[mf] = *(const half8*)(act + arow * FP_F + kk);
    }
    const float* wr = wc + (size_t)(n0 + (l & 31)) * FP_F + kk;
    v4f w0 = *(const v4f*)(wr);
    v4f w1 = *(const v4f*)(wr + 4);
    half8 bh;
    #pragma unroll
    for (int j = 0; j < 4; ++j) {
      bh[j] = (_Float16)w0[j];
      bh[4 + j] = (_Float16)w1[j];
    }
    #pragma unroll
    for (int mf = 0; mf < 2; ++mf)
      facc[mf] = __builtin_amdgcn_mfma_f32_32x32x16_f16(ah[mf], bh, facc[mf], 0, 0, 0);
  }

  const int col = n0 + (l & 31);
  #pragma unroll
  for (int mf = 0; mf < 2; ++mf)
    #pragma unroll
    for (int rr = 0; rr < 16; ++rr) {
      const int row = row0 + mf * 32 + (rr & 3) + 8 * (rr >> 2) + hi4;
      out[(size_t)row * OUT_F + col] = facc[mf][rr] + bs;
    }
}

extern "C" void kernel_launch(void* const* d_in, const int* in_sizes, int n_in,
                              void* d_out, int out_size, void* d_ws, size_t ws_size,
                              hipStream_t stream) {
  const float* x      = (const float*)d_in[0];
  const int*   qw     = (const int*)d_in[1];
  const float* scol   = (const float*)d_in[2];
  const float* wcache = (const float*)d_in[3];
  const int*   ind    = (const int*)d_in[4];
  const float* bias   = (const float*)d_in[5];
  float* out = (float*)d_out;

  const size_t act_off = (size_t)NROWS * IN_F;                      // 2 MB
  const size_t xs_off  = act_off + (size_t)NROWS * FP_F * 2;        // +256 KB

  signed char* qx = (signed char*)d_ws;
  _Float16* act   = (_Float16*)((char*)d_ws + act_off);
  float* xscale   = (float*)((char*)d_ws + xs_off);

  quant_kernel<<<NROWS, 256, 0, stream>>>(x, ind, qx, act, xscale);
  gemm_kernel<<<NGEMM, 256, 0, stream>>>(qx, qw, scol, wcache, bias, act, xscale, out);
}

// Round 9
// 106.402 us; speedup vs baseline: 1.2689x; 1.2689x over previous
//
#include <hip/hip_runtime.h>
#include <hip/hip_fp16.h>

#define IN_F 4096
#define OUT_F 11008
#define FP_F 256
#define NROWS 512
#define BN 32
#define BM 256
#define NGEMM ((OUT_F / BN) * (NROWS / BM))  // 344 * 2 = 688

typedef int v4i __attribute__((ext_vector_type(4)));
typedef int v16i __attribute__((ext_vector_type(16)));
typedef float v4f __attribute__((ext_vector_type(4)));
typedef float v16f __attribute__((ext_vector_type(16)));
typedef _Float16 half8 __attribute__((ext_vector_type(8)));

__device__ __forceinline__ int pack4(v4i a) {
  return (int)((unsigned)(a[0] & 255) | ((unsigned)(a[1] & 255) << 8) |
               ((unsigned)(a[2] & 255) << 16) | ((unsigned)(a[3] & 255) << 24));
}

// 32x32 int8 fragment layout (verified r6-r8): operand lane l = row (l&31),
// k = kb32*32 + (l>>5)*16 + [0..16).

// ---------------- quant: x -> int8 qx (fragment layout) + act + xscale -------
__global__ __launch_bounds__(256) void quant_kernel(
    const float* __restrict__ x, const int* __restrict__ ind,
    signed char* __restrict__ qx, _Float16* __restrict__ act,
    float* __restrict__ xscale)
{
  const int m = blockIdx.x;
  const int t = threadIdx.x;
  __shared__ unsigned char zm[IN_F];
  __shared__ float wmax[4];
  int* zmi = (int*)zm;
  #pragma unroll
  for (int i = 0; i < IN_F / 4 / 256; ++i) zmi[t + i * 256] = 0;
  __syncthreads();
  const int idx = ind[t];
  zm[idx] = 1;
  __syncthreads();

  const float* xr = x + (size_t)m * IN_F;
  float v[16];
  float amax = 0.f;
  const int k0 = t * 16;
  #pragma unroll
  for (int q = 0; q < 4; ++q) {
    v4f f = *(const v4f*)(xr + k0 + q * 4);
    #pragma unroll
    for (int j = 0; j < 4; ++j) {
      float mv = zm[k0 + q * 4 + j] ? 0.f : f[j];
      v[q * 4 + j] = mv;
      amax = fmaxf(amax, fabsf(mv));
    }
  }
  #pragma unroll
  for (int off = 32; off >= 1; off >>= 1)
    amax = fmaxf(amax, __shfl_xor(amax, off));
  if ((t & 63) == 0) wmax[t >> 6] = amax;
  __syncthreads();
  amax = fmaxf(fmaxf(wmax[0], wmax[1]), fmaxf(wmax[2], wmax[3]));
  const float scale = fmaxf(amax / 127.0f, 1e-8f);
  if (t == 0) xscale[m] = scale;
  const float inv = 1.0f / scale;

  union { signed char b[16]; v4i w4; } pk;
  #pragma unroll
  for (int j = 0; j < 16; ++j) {
    float qv = rintf(v[j] * inv);            // round-half-even, like jnp.round
    qv = fminf(fmaxf(qv, -128.f), 127.f);
    pk.b[j] = (signed char)qv;
  }
  ((v4i*)qx)[((m >> 5) * 128 + (t >> 1)) * 64 + (m & 31) + 32 * (t & 1)] = pk.w4;

  act[m * FP_F + t] = (_Float16)xr[idx];
}

// ---------------- fused gemm: q_weight read once/mseg, packed in-flight -----
// Tile 256(M) x 32(N), 4 waves, wave = 64 rows x 32 cols (2 mfrags 32x32x32).
// K in 8 chunks of 512. Staging: every wave-instruction reads 1KB FULLY
// CONTIGUOUS from ONE q_weight row (lane i = ints [span*256+4i,+4) of row
// 8w+(j>>1)) -- 16 segments/instr, not 64 (r8's 1.5TB/s bug). Pack ->
// one b32 LDS store, XOR-swizzled (col = kb32 ^ (row&15)): 2 lanes/bank
// (free). MFMA ds_read_b128 un-swizzles per-lane. One barrier per chunk;
// next chunk's loads issued before the MFMA phase.
__global__ __launch_bounds__(256) void gemm_kernel(
    const signed char* __restrict__ qx, const int* __restrict__ qw,
    const float* __restrict__ scol, const float* __restrict__ wc,
    const float* __restrict__ bias, const _Float16* __restrict__ act,
    const float* __restrict__ xscale, float* __restrict__ out)
{
  __shared__ __align__(16) signed char lds[2][16384];   // [buf][lf*256+col*16+b]
  const int tid = threadIdx.x;
  const int w = tid >> 6;
  const int l = tid & 63;
  // bijective XCD swizzle (688 = 8*86): mseg pair of an ntile adjacent on XCD
  const int orig = blockIdx.x;
  const int wgid = (orig & 7) * 86 + (orig >> 3);
  const int mseg = wgid & 1;
  const int ntile = wgid >> 1;
  const int n0 = ntile * BN;
  const int row0 = mseg * BM + w * 64;

  const v4i* qw4 = (const v4i*)qw;          // row stride 1024 v4i
  const v4i* qx4 = (const v4i*)qx;
  const int aB0 = ((mseg * 8 + w * 2 + 0) * 128) * 64 + l;
  const int aB1 = ((mseg * 8 + w * 2 + 1) * 128) * 64 + l;

  v4i r[16];

#define LOADC(C) do {                                                         \
    _Pragma("unroll")                                                         \
    for (int j = 0; j < 16; ++j)                                              \
      r[j] = qw4[(size_t)(n0 + 8 * w + (j >> 1)) * 1024 +                     \
                 (C) * 128 + (j & 1) * 64 + l];                               \
  } while (0)

#define WRITEC(C) do {                                                        \
    _Pragma("unroll")                                                         \
    for (int j = 0; j < 16; ++j) {                                            \
      const int R = 8 * w + (j >> 1);                                         \
      const int kb32l = (j & 1) * 8 + (l >> 3);                               \
      const int lf = R + 32 * ((l >> 2) & 1);                                 \
      const int col = kb32l ^ (R & 15);                                       \
      *(int*)(&lds[(C) & 1][lf * 256 + col * 16 + 4 * (l & 3)]) = pack4(r[j]);\
    }                                                                         \
  } while (0)

  LOADC(0);
  WRITEC(0);
  __syncthreads();

  v16i acc[2] = {};
  for (int c = 0; c < 8; ++c) {
    if (c < 7) LOADC(c + 1);                 // contiguous issue, hides under MFMA
    const int cb = c & 1;
    #pragma unroll
    for (int kc = 0; kc < 16; ++kc) {
      v4i bf = *(const v4i*)(&lds[cb][l * 256 + (kc ^ (l & 15)) * 16]);
      v4i a0 = qx4[aB0 + (c * 16 + kc) * 64];
      v4i a1 = qx4[aB1 + (c * 16 + kc) * 64];
      acc[0] = __builtin_amdgcn_mfma_i32_32x32x32_i8(a0, bf, acc[0], 0, 0, 0);
      acc[1] = __builtin_amdgcn_mfma_i32_32x32x32_i8(a1, bf, acc[1], 0, 0, 0);
    }
    if (c < 7) WRITEC(c + 1);
    __syncthreads();
  }
#undef LOADC
#undef WRITEC

  // epilogue: C/D 32x32 mapping: col = l&31, row = (r&3)+8*(r>>2)+4*(l>>5)
  const float sc = scol[n0 + (l & 31)];
  const float bs = bias[n0 + (l & 31)];
  const int hi4 = 4 * (l >> 5);
  float xs[2][16];
  #pragma unroll
  for (int mf = 0; mf < 2; ++mf)
    #pragma unroll
    for (int rr = 0; rr < 16; ++rr)
      xs[mf][rr] = xscale[row0 + mf * 32 + (rr & 3) + 8 * (rr >> 2) + hi4];

  v16f facc[2];
  #pragma unroll
  for (int mf = 0; mf < 2; ++mf)
    #pragma unroll
    for (int rr = 0; rr < 16; ++rr)
      facc[mf][rr] = (float)acc[mf][rr] * xs[mf][rr] * sc;

  // outlier fp phase: K=256 in 16 steps of 16, 32x32x16 f16 MFMA
  #pragma unroll
  for (int ks = 0; ks < 16; ++ks) {
    const int kk = ks * 16 + (l >> 5) * 8;
    half8 ah[2];
    #pragma unroll
    for (int mf = 0; mf < 2; ++mf) {
      const int arow = row0 + mf * 32 + (l & 31);
      ah[mf] = *(const half8*)(act + arow * FP_F + kk);
    }
    const float* wr = wc + (size_t)(n0 + (l & 31)) * FP_F + kk;
    v4f w0 = *(const v4f*)(wr);
    v4f w1 = *(const v4f*)(wr + 4);
    half8 bh;
    #pragma unroll
    for (int j = 0; j < 4; ++j) {
      bh[j] = (_Float16)w0[j];
      bh[4 + j] = (_Float16)w1[j];
    }
    #pragma unroll
    for (int mf = 0; mf < 2; ++mf)
      facc[mf] = __builtin_amdgcn_mfma_f32_32x32x16_f16(ah[mf], bh, facc[mf], 0, 0, 0);
  }

  const int col = n0 + (l & 31);
  #pragma unroll
  for (int mf = 0; mf < 2; ++mf)
    #pragma unroll
    for (int rr = 0; rr < 16; ++rr) {
      const int row = row0 + mf * 32 + (rr & 3) + 8 * (rr >> 2) + hi4;
      out[(size_t)row * OUT_F + col] = facc[mf][rr] + bs;
    }
}

extern "C" void kernel_launch(void* const* d_in, const int* in_sizes, int n_in,
                              void* d_out, int out_size, void* d_ws, size_t ws_size,
                              hipStream_t stream) {
  const float* x      = (const float*)d_in[0];
  const int*   qw     = (const int*)d_in[1];
  const float* scol   = (const float*)d_in[2];
  const float* wcache = (const float*)d_in[3];
  const int*   ind    = (const int*)d_in[4];
  const float* bias   = (const float*)d_in[5];
  float* out = (float*)d_out;

  const size_t act_off = (size_t)NROWS * IN_F;                      // 2 MB
  const size_t xs_off  = act_off + (size_t)NROWS * FP_F * 2;        // +256 KB

  signed char* qx = (signed char*)d_ws;
  _Float16* act   = (_Float16*)((char*)d_ws + act_off);
  float* xscale   = (float*)((char*)d_ws + xs_off);

  quant_kernel<<<NROWS, 256, 0, stream>>>(x, ind, qx, act, xscale);
  gemm_kernel<<<NGEMM, 256, 0, stream>>>(qx, qw, scol, wcache, bias, act, xscale, out);
}